// Round 1
// baseline (742.595 us; speedup 1.0000x reference)
//
#include <hip/hip_runtime.h>

// GNN surrogate, fully fused fp32 version.
// Math rewrites (exact): last aggregation folded into v[j]=mean_i adj[i,j];
// readout folded through layer-3: u = W2[2] @ W_ro, c_out = (b2[2]·W_ro)*sum(v) + b_ro.
// Total ~56 GFLOP fp32 -> VALU-bound (no fp32 MFMA on CDNA4).

namespace {
constexpr int N  = 128;   // nodes
constexpr int H  = 32;    // hidden
constexpr int NB = 2;     // batches per block
// ws layout (float offsets)
constexpr int WS_ADJT = 0;       // [128*128]: adjT[j*128+i] = adj[i*128+j]
constexpr int WS_V    = 16384;   // [128]: v[j] = mean_i adj[i][j]
constexpr int WS_U    = 16512;   // [32]:  u[c] = sum_k W2[2][c][k] * W_ro[k]
constexpr int WS_C    = 16544;   // [1]:   c_out = (b2[2]·W_ro)*sum_j v[j] + b_ro
}

__global__ void prep_kernel(const float* __restrict__ adj,
                            const float* __restrict__ W2,
                            const float* __restrict__ b2,
                            const float* __restrict__ W_ro,
                            const float* __restrict__ b_ro,
                            float* __restrict__ ws) {
  const int tid = threadIdx.x;
  // transpose adj into ws
  for (int idx = tid; idx < N * N; idx += 256) {
    const int i = idx >> 7, j = idx & (N - 1);
    ws[WS_ADJT + j * N + i] = adj[idx];
  }
  // v[j] = mean over rows i of adj[i][j]
  if (tid < N) {
    float s = 0.f;
    for (int i = 0; i < N; ++i) s += adj[i * N + tid];
    ws[WS_V + tid] = s * (1.0f / N);
  }
  // u[c] = sum_k W2[layer2][c][k] * W_ro[k]
  if (tid < H) {
    float s = 0.f;
    for (int k = 0; k < H; ++k) s += W2[2 * H * H + tid * H + k] * W_ro[k];
    ws[WS_U + tid] = s;
  }
  __syncthreads();
  if (tid == 0) {
    float c2r = 0.f;
    for (int k = 0; k < H; ++k) c2r += b2[2 * H + k] * W_ro[k];
    float S = 0.f;
    for (int j = 0; j < N; ++j) S += ws[WS_V + j];
    ws[WS_C] = c2r * S + b_ro[0];
  }
}

__global__ __launch_bounds__(256, 4)
void gnn_fused(const float* __restrict__ x,
               const float* __restrict__ W_lift,
               const float* __restrict__ b_lift,
               const float* __restrict__ W1,
               const float* __restrict__ b1,
               const float* __restrict__ W2,
               const float* __restrict__ b2,
               const float* __restrict__ ws,
               float* __restrict__ out) {
  // local/h staging: [batch][node][feat], rows are 128B (float4-friendly).
  __shared__ float lbuf[NB][N][H];   // 32 KB
  __shared__ float red[4];

  const int tid = threadIdx.x;
  // row mapping (lift / MLP / readout): thread = (bl, n)
  const int bl = tid >> 7;        // batch within block: 0/1
  const int n  = tid & (N - 1);   // node 0..127
  const int b  = blockIdx.x * NB + bl;
  // tile mapping (aggregation): thread = (bl, ioct, kq)
  const int ioct = (tid & 127) >> 3;   // 0..15 -> output rows ioct*8 .. +7
  const int kq   = tid & 7;            // 0..7  -> feature quad kq*4 .. +3
  const int i0   = ioct * 8;
  const int kq4  = kq * 4;
  const float* __restrict__ adjT = ws + WS_ADJT;

  float h[H];

  // ---- lift: h = x[b,n,:] @ W_lift + b_lift ----
  {
    const size_t xo = (size_t)b * (N * 3) + (size_t)n * 3;
    const float x0 = x[xo + 0], x1 = x[xo + 1], x2 = x[xo + 2];
#pragma unroll
    for (int k = 0; k < H; ++k) {
      float a = b_lift[k];
      a = fmaf(x0, W_lift[0 * H + k], a);
      a = fmaf(x1, W_lift[1 * H + k], a);
      a = fmaf(x2, W_lift[2 * H + k], a);
      h[k] = a;
    }
  }

  // ---- layers 0,1: node-MLP then adjacency aggregation ----
  for (int l = 0; l < 2; ++l) {
    const float* __restrict__ w1  = W1 + l * H * H;
    const float* __restrict__ bb1 = b1 + l * H;
    const float* __restrict__ w2  = W2 + l * H * H;
    const float* __restrict__ bb2 = b2 + l * H;

    float t[H];
#pragma unroll
    for (int k = 0; k < H; ++k) {
      float a = bb1[k];
#pragma unroll
      for (int c = 0; c < H; ++c) a = fmaf(h[c], w1[c * H + k], a);
      t[k] = fmaxf(a, 0.f);
    }
#pragma unroll
    for (int k = 0; k < H; ++k) {
      float a = bb2[k];
#pragma unroll
      for (int c = 0; c < H; ++c) a = fmaf(t[c], w2[c * H + k], a);
      lbuf[bl][n][k] = a;   // consecutive k -> compiler merges to ds_write_b128
    }
    __syncthreads();

    // aggregation: out[i,k] = sum_j adjT[j][i] * local[j][k]
    float acc[8][4];
#pragma unroll
    for (int r = 0; r < 8; ++r)
#pragma unroll
      for (int c = 0; c < 4; ++c) acc[r][c] = 0.f;

#pragma unroll 4
    for (int j = 0; j < N; ++j) {
      const float4 lv = *reinterpret_cast<const float4*>(&lbuf[bl][j][kq4]);
      const float4 a0 = *reinterpret_cast<const float4*>(&adjT[j * N + i0]);
      const float4 a1 = *reinterpret_cast<const float4*>(&adjT[j * N + i0 + 4]);
      const float av[8] = {a0.x, a0.y, a0.z, a0.w, a1.x, a1.y, a1.z, a1.w};
#pragma unroll
      for (int r = 0; r < 8; ++r) {
        acc[r][0] = fmaf(av[r], lv.x, acc[r][0]);
        acc[r][1] = fmaf(av[r], lv.y, acc[r][1]);
        acc[r][2] = fmaf(av[r], lv.z, acc[r][2]);
        acc[r][3] = fmaf(av[r], lv.w, acc[r][3]);
      }
    }
    __syncthreads();   // all reads of lbuf done before overwrite

#pragma unroll
    for (int r = 0; r < 8; ++r) {
      float4 v4;
      v4.x = acc[r][0]; v4.y = acc[r][1]; v4.z = acc[r][2]; v4.w = acc[r][3];
      *reinterpret_cast<float4*>(&lbuf[bl][i0 + r][kq4]) = v4;
    }
    __syncthreads();   // aggregated h visible

    // reload this thread's row as next-layer h
#pragma unroll
    for (int k = 0; k < H; ++k) h[k] = lbuf[bl][n][k];
  }

  // ---- layer 2 (folded): s = relu(h @ W1[2] + b1[2]) · u ; out = sum_n v[n]*s + c_out
  {
    const float* __restrict__ w1  = W1 + 2 * H * H;
    const float* __restrict__ bb1 = b1 + 2 * H;
    float s = 0.f;
#pragma unroll
    for (int k = 0; k < H; ++k) {
      float a = bb1[k];
#pragma unroll
      for (int c = 0; c < H; ++c) a = fmaf(h[c], w1[c * H + k], a);
      s = fmaf(fmaxf(a, 0.f), ws[WS_U + k], s);
    }
    float val = ws[WS_V + n] * s;
    // wave-64 reduction
#pragma unroll
    for (int off = 32; off > 0; off >>= 1) val += __shfl_down(val, off, 64);
    if ((tid & 63) == 0) red[tid >> 6] = val;
    __syncthreads();
    if (tid == 0)   out[blockIdx.x * NB + 0] = red[0] + red[1] + ws[WS_C];
    if (tid == 128) out[blockIdx.x * NB + 1] = red[2] + red[3] + ws[WS_C];
  }
}

extern "C" void kernel_launch(void* const* d_in, const int* in_sizes, int n_in,
                              void* d_out, int out_size, void* d_ws, size_t ws_size,
                              hipStream_t stream) {
  const float* x      = (const float*)d_in[0];
  const float* adj    = (const float*)d_in[1];
  const float* W_lift = (const float*)d_in[2];
  const float* b_lift = (const float*)d_in[3];
  const float* W1     = (const float*)d_in[4];
  const float* b1     = (const float*)d_in[5];
  const float* W2     = (const float*)d_in[6];
  const float* b2     = (const float*)d_in[7];
  const float* W_ro   = (const float*)d_in[8];
  const float* b_ro   = (const float*)d_in[9];
  float* ws  = (float*)d_ws;
  float* o   = (float*)d_out;

  const int B = in_sizes[0] / (N * 3);   // 16384
  hipLaunchKernelGGL(prep_kernel, dim3(1), dim3(256), 0, stream,
                     adj, W2, b2, W_ro, b_ro, ws);
  hipLaunchKernelGGL(gnn_fused, dim3(B / NB), dim3(256), 0, stream,
                     x, W_lift, b_lift, W1, b1, W2, b2, ws, o);
}

// Round 2
// 285.552 us; speedup vs baseline: 2.6006x; 2.6006x over previous
//
#include <hip/hip_runtime.h>

// GNN surrogate — f16 MFMA version (16x16x32, fp32 accumulate).
// Stages alternate X / X^T so every C-fragment write into LDS is a contiguous
// ds_write_b64 (r-index of C maps to consecutive elements of transposed buf).
// Folds (exact): v[j]=mean_i adj[i,j] absorbs layer-3 aggregation;
// u = W2[2]@W_ro, c = (b2[2]·W_ro)*sum(v) + b_ro absorbs the readout.

typedef _Float16 f16;
typedef __attribute__((ext_vector_type(8))) _Float16 half8;
typedef __attribute__((ext_vector_type(4))) _Float16 half4;
typedef __attribute__((ext_vector_type(4))) float f32x4;

namespace {
constexpr int N = 128, H = 32;
// ws byte layout
constexpr int WS_ADJF = 0;       // f16 [128][128] adj row-major      (32768 B)
constexpr int WS_W1T  = 32768;   // f16 [3][32][32] W1^T [fout][fin]  (6144 B)
constexpr int WS_W2T  = 38912;   // f16 [3][32][32] W2^T [fout][fmid] (6144 B)
constexpr int WS_V    = 45056;   // f32 [128] v[j] = mean_i adj[i][j]
constexpr int WS_U    = 45568;   // f32 [32]  u[k] = sum_c W2[2][k][c]*W_ro[c]
constexpr int WS_C    = 45696;   // f32 [1]
}

__global__ void prep(const float* __restrict__ adj,
                     const float* __restrict__ W1,
                     const float* __restrict__ W2,
                     const float* __restrict__ b2,
                     const float* __restrict__ W_ro,
                     const float* __restrict__ b_ro,
                     char* __restrict__ ws) {
  const int tid = threadIdx.x;
  const int gid = blockIdx.x * 256 + tid;
  f16* adjf = (f16*)(ws + WS_ADJF);
  f16* w1t  = (f16*)(ws + WS_W1T);
  f16* w2t  = (f16*)(ws + WS_W2T);
  float* v  = (float*)(ws + WS_V);
  float* u  = (float*)(ws + WS_U);
  float* cp = (float*)(ws + WS_C);

  for (int idx = gid; idx < N * N; idx += 2048) adjf[idx] = (f16)adj[idx];
  for (int idx = gid; idx < 3 * H * H; idx += 2048) {
    const int l = idx / (H * H), rem = idx % (H * H);
    const int fo = rem / H, fi = rem % H;
    w1t[idx] = (f16)W1[l * H * H + fi * H + fo];
    w2t[idx] = (f16)W2[l * H * H + fi * H + fo];
  }
  if (blockIdx.x == 0) {
    if (tid < N) {
      float s = 0.f;
      for (int i = 0; i < N; ++i) s += adj[i * N + tid];
      v[tid] = s * (1.0f / N);
    }
    if (tid < H) {
      float s = 0.f;
      for (int c = 0; c < H; ++c) s += W2[2 * H * H + tid * H + c] * W_ro[c];
      u[tid] = s;
    }
    __syncthreads();
    if (tid == 0) {
      float c2r = 0.f;
      for (int k = 0; k < H; ++k) c2r += b2[2 * H + k] * W_ro[k];
      float S = 0.f;
      for (int j = 0; j < N; ++j) S += v[j];
      cp[0] = c2r * S + b_ro[0];
    }
  }
}

__global__ __launch_bounds__(256, 4)
void gnn_mfma(const float* __restrict__ x,
              const float* __restrict__ W_lift,
              const float* __restrict__ b_lift,
              const float* __restrict__ b1,
              const float* __restrict__ b2,
              const char* __restrict__ ws,
              float* __restrict__ out) {
  // bufH: H (and T, overlaid) [node][feat], row stride 48 f16 = 96 B (16B-aligned)
  // bufL: L^T [feat][node], row stride 136 f16 = 272 B (16B-aligned)
  __shared__ f16 bufH[N][48];
  __shared__ f16 bufL[H][136];
  __shared__ float red[4];

  const f16* adjf = (const f16*)(ws + WS_ADJF);
  const f16* w1t  = (const f16*)(ws + WS_W1T);
  const f16* w2t  = (const f16*)(ws + WS_W2T);
  const float* v  = (const float*)(ws + WS_V);
  const float* u  = (const float*)(ws + WS_U);
  const float* cp = (const float*)(ws + WS_C);

  const int tid  = threadIdx.x;
  const int wave = tid >> 6;
  const int lane = tid & 63;
  const int lrow = lane & 15;   // m/n index within 16-tile
  const int quad = lane >> 4;   // 0..3
  const int b    = blockIdx.x;

  // ---- lift: H0[node][k] = x[b,node,:]@W_lift + b_lift (fp32 VALU, -> f16) ----
  {
    const int node = tid >> 1, half = tid & 1;
    const float* xr = x + (size_t)b * (N * 3) + node * 3;
    const float x0 = xr[0], x1 = xr[1], x2 = xr[2];
    half8 hlo, hhi;
#pragma unroll
    for (int k = 0; k < 8; ++k) {
      const int k0 = half * 16 + k, k1 = half * 16 + 8 + k;
      hlo[k] = (f16)fmaf(x0, W_lift[k0], fmaf(x1, W_lift[H + k0], fmaf(x2, W_lift[2 * H + k0], b_lift[k0])));
      hhi[k] = (f16)fmaf(x0, W_lift[k1], fmaf(x1, W_lift[H + k1], fmaf(x2, W_lift[2 * H + k1], b_lift[k1])));
    }
    *(half8*)&bufH[node][half * 16]     = hlo;
    *(half8*)&bufH[node][half * 16 + 8] = hhi;
  }
  __syncthreads();

  const f32x4 zero = {0.f, 0.f, 0.f, 0.f};

  for (int l = 0; l < 3; ++l) {
    // ======== stage A: T^T = W1^T·H^T  (M=fout 2 tiles, N=node 8 tiles, K=32)
    // A-op: w1t[fout][fin]; B-op: bufH[node][fin]
    const half8 a0 = *(const half8*)(w1t + l * H * H + lrow * H + quad * 8);
    const half8 a1 = *(const half8*)(w1t + l * H * H + (16 + lrow) * H + quad * 8);
    f32x4 c0[2], c1[2];
#pragma unroll
    for (int g = 0; g < 2; ++g) {
      const int nt = wave * 2 + g;
      const half8 bf = *(const half8*)&bufH[nt * 16 + lrow][quad * 8];
      c0[g] = __builtin_amdgcn_mfma_f32_16x16x32_f16(a0, bf, zero, 0, 0, 0);
      c1[g] = __builtin_amdgcn_mfma_f32_16x16x32_f16(a1, bf, zero, 0, 0, 0);
    }

    if (l == 2) {
      // folded readout: out = sum_{fmid,node} relu(T2^T)[fmid][node]*u[fmid]*v[node] + c
      const float4 u0  = *(const float4*)(u + quad * 4);
      const float4 u1  = *(const float4*)(u + 16 + quad * 4);
      const float4 bb0 = *(const float4*)(b1 + 2 * H + quad * 4);
      const float4 bb1 = *(const float4*)(b1 + 2 * H + 16 + quad * 4);
      float partial = 0.f;
#pragma unroll
      for (int g = 0; g < 2; ++g) {
        const int nt = wave * 2 + g;
        const float vn = v[nt * 16 + lrow];
        partial += (fmaxf(c0[g][0] + bb0.x, 0.f) * u0.x + fmaxf(c0[g][1] + bb0.y, 0.f) * u0.y +
                    fmaxf(c0[g][2] + bb0.z, 0.f) * u0.z + fmaxf(c0[g][3] + bb0.w, 0.f) * u0.w +
                    fmaxf(c1[g][0] + bb1.x, 0.f) * u1.x + fmaxf(c1[g][1] + bb1.y, 0.f) * u1.y +
                    fmaxf(c1[g][2] + bb1.z, 0.f) * u1.z + fmaxf(c1[g][3] + bb1.w, 0.f) * u1.w) * vn;
      }
#pragma unroll
      for (int off = 32; off > 0; off >>= 1) partial += __shfl_down(partial, off, 64);
      if (lane == 0) red[wave] = partial;
      __syncthreads();
      if (tid == 0) out[b] = red[0] + red[1] + red[2] + red[3] + cp[0];
      return;
    }

    // bias + relu, write T[node][fmid] (contiguous half4 per C frag)
    {
      const float4 bb0 = *(const float4*)(b1 + l * H + quad * 4);
      const float4 bb1 = *(const float4*)(b1 + l * H + 16 + quad * 4);
#pragma unroll
      for (int g = 0; g < 2; ++g) {
        const int node = (wave * 2 + g) * 16 + lrow;
        half4 t0, t1;
        t0[0] = (f16)fmaxf(c0[g][0] + bb0.x, 0.f); t0[1] = (f16)fmaxf(c0[g][1] + bb0.y, 0.f);
        t0[2] = (f16)fmaxf(c0[g][2] + bb0.z, 0.f); t0[3] = (f16)fmaxf(c0[g][3] + bb0.w, 0.f);
        t1[0] = (f16)fmaxf(c1[g][0] + bb1.x, 0.f); t1[1] = (f16)fmaxf(c1[g][1] + bb1.y, 0.f);
        t1[2] = (f16)fmaxf(c1[g][2] + bb1.z, 0.f); t1[3] = (f16)fmaxf(c1[g][3] + bb1.w, 0.f);
        *(half4*)&bufH[node][quad * 4]      = t0;   // fmid = quad*4+r       (mt=0)
        *(half4*)&bufH[node][16 + quad * 4] = t1;   // fmid = 16+quad*4+r    (mt=1)
      }
    }
    __syncthreads();

    // ======== stage B: L = T·W2  (M=node 8 tiles, N=fout 2 tiles, K=32)
    // A-op: bufH(T)[node][fmid]; B-op: w2t[fout][fmid]
    {
      const half8 wb0 = *(const half8*)(w2t + l * H * H + lrow * H + quad * 8);
      const half8 wb1 = *(const half8*)(w2t + l * H * H + (16 + lrow) * H + quad * 8);
      const float bias0 = b2[l * H + lrow];
      const float bias1 = b2[l * H + 16 + lrow];
#pragma unroll
      for (int g = 0; g < 2; ++g) {
        const int mt = wave * 2 + g;
        const half8 af = *(const half8*)&bufH[mt * 16 + lrow][quad * 8];
        const f32x4 d0 = __builtin_amdgcn_mfma_f32_16x16x32_f16(af, wb0, zero, 0, 0, 0);
        const f32x4 d1 = __builtin_amdgcn_mfma_f32_16x16x32_f16(af, wb1, zero, 0, 0, 0);
        half4 o0, o1;
        o0[0] = (f16)(d0[0] + bias0); o0[1] = (f16)(d0[1] + bias0);
        o0[2] = (f16)(d0[2] + bias0); o0[3] = (f16)(d0[3] + bias0);
        o1[0] = (f16)(d1[0] + bias1); o1[1] = (f16)(d1[1] + bias1);
        o1[2] = (f16)(d1[2] + bias1); o1[3] = (f16)(d1[3] + bias1);
        // L^T[fout][node], node = mt*16+quad*4+r contiguous
        *(half4*)&bufL[lrow][mt * 16 + quad * 4]      = o0;
        *(half4*)&bufL[16 + lrow][mt * 16 + quad * 4] = o1;
      }
    }
    __syncthreads();

    // ======== stage C: H'^T = L^T·adj^T  (M=feat 2, N=node_i 8, K=128 = 4 mfma)
    // A-op: bufL[feat][node_j]; B-op: adjf[i][j] (global, L1/L2-resident)
    {
      half8 af[2][4];
#pragma unroll
      for (int mt = 0; mt < 2; ++mt)
#pragma unroll
        for (int kt = 0; kt < 4; ++kt)
          af[mt][kt] = *(const half8*)&bufL[mt * 16 + lrow][kt * 32 + quad * 8];
#pragma unroll
      for (int g = 0; g < 2; ++g) {
        const int nt = wave * 2 + g;
        f32x4 h0 = zero, h1 = zero;
#pragma unroll
        for (int kt = 0; kt < 4; ++kt) {
          const half8 bf = *(const half8*)(adjf + (nt * 16 + lrow) * N + kt * 32 + quad * 8);
          h0 = __builtin_amdgcn_mfma_f32_16x16x32_f16(af[0][kt], bf, h0, 0, 0, 0);
          h1 = __builtin_amdgcn_mfma_f32_16x16x32_f16(af[1][kt], bf, h1, 0, 0, 0);
        }
        half4 w0, w1;
        w0[0] = (f16)h0[0]; w0[1] = (f16)h0[1]; w0[2] = (f16)h0[2]; w0[3] = (f16)h0[3];
        w1[0] = (f16)h1[0]; w1[1] = (f16)h1[1]; w1[2] = (f16)h1[2]; w1[3] = (f16)h1[3];
        // H'[node][feat], feat = mt*16+quad*4+r contiguous
        *(half4*)&bufH[nt * 16 + lrow][quad * 4]      = w0;
        *(half4*)&bufH[nt * 16 + lrow][16 + quad * 4] = w1;
      }
    }
    __syncthreads();
  }
}

extern "C" void kernel_launch(void* const* d_in, const int* in_sizes, int n_in,
                              void* d_out, int out_size, void* d_ws, size_t ws_size,
                              hipStream_t stream) {
  const float* x      = (const float*)d_in[0];
  const float* adj    = (const float*)d_in[1];
  const float* W_lift = (const float*)d_in[2];
  const float* b_lift = (const float*)d_in[3];
  const float* W1     = (const float*)d_in[4];
  const float* b1     = (const float*)d_in[5];
  const float* W2     = (const float*)d_in[6];
  const float* b2     = (const float*)d_in[7];
  const float* W_ro   = (const float*)d_in[8];
  const float* b_ro   = (const float*)d_in[9];
  char* ws = (char*)d_ws;
  float* o = (float*)d_out;

  const int B = in_sizes[0] / (N * 3);   // 16384
  hipLaunchKernelGGL(prep, dim3(8), dim3(256), 0, stream,
                     adj, W1, W2, b2, W_ro, b_ro, ws);
  hipLaunchKernelGGL(gnn_mfma, dim3(B), dim3(256), 0, stream,
                     x, W_lift, b_lift, b1, b2, (const char*)ws, o);
}

// Round 3
// 226.241 us; speedup vs baseline: 3.2823x; 1.2622x over previous
//
#include <hip/hip_runtime.h>

// GNN surrogate — f16 MFMA, wave-per-batch, BARRIER-FREE main kernel.
// Each wave owns one batch in a private 10 KB LDS slab; bufH[128][40] and
// bufL[32][136] overlap (all aliased reads precede the stores in program
// order; DS ops within a wave execute in order -> safe in-place reuse).
// Folds (exact): v[j]=mean_i adj[i,j] absorbs layer-3 aggregation;
// u = W2[2]@W_ro, c = (b2[2]·W_ro)*sum(v) + b_ro absorbs the readout.

typedef _Float16 f16;
typedef __attribute__((ext_vector_type(8))) _Float16 half8;
typedef __attribute__((ext_vector_type(4))) _Float16 half4;
typedef __attribute__((ext_vector_type(4))) float f32x4;

namespace {
constexpr int N = 128, H = 32;
// ws byte layout
constexpr int WS_ADJF = 0;       // f16 [128][128] adj row-major      (32768 B)
constexpr int WS_W1T  = 32768;   // f16 [3][32][32] W1^T [fout][fin]  (6144 B)
constexpr int WS_W2T  = 38912;   // f16 [3][32][32] W2^T [fout][fmid] (6144 B)
constexpr int WS_V    = 45056;   // f32 [128] v[j] = mean_i adj[i][j]
constexpr int WS_U    = 45568;   // f32 [32]  u[k] = sum_c W2[2][k][c]*W_ro[c]
constexpr int WS_C    = 45696;   // f32 [1]
constexpr int RS = 40;    // bufH row stride, f16 (80 B = 16Bx5: aligned, conflict-floor)
constexpr int LS = 136;   // bufL row stride, f16 (272 B = 16Bx17)
}

__global__ void prep(const float* __restrict__ adj,
                     const float* __restrict__ W1,
                     const float* __restrict__ W2,
                     const float* __restrict__ b2,
                     const float* __restrict__ W_ro,
                     const float* __restrict__ b_ro,
                     char* __restrict__ ws) {
  const int tid = threadIdx.x;
  const int gid = blockIdx.x * 256 + tid;
  f16* adjf = (f16*)(ws + WS_ADJF);
  f16* w1t  = (f16*)(ws + WS_W1T);
  f16* w2t  = (f16*)(ws + WS_W2T);
  float* v  = (float*)(ws + WS_V);
  float* u  = (float*)(ws + WS_U);
  float* cp = (float*)(ws + WS_C);

  for (int idx = gid; idx < N * N; idx += 2048) adjf[idx] = (f16)adj[idx];
  for (int idx = gid; idx < 3 * H * H; idx += 2048) {
    const int l = idx / (H * H), rem = idx % (H * H);
    const int fo = rem / H, fi = rem % H;
    w1t[idx] = (f16)W1[l * H * H + fi * H + fo];
    w2t[idx] = (f16)W2[l * H * H + fi * H + fo];
  }
  if (blockIdx.x == 0) {
    __shared__ float sred[N];
    if (tid < N) {
      float s = 0.f;
      for (int i = 0; i < N; ++i) s += adj[i * N + tid];
      v[tid] = s * (1.0f / N);
      sred[tid] = s * (1.0f / N);
    }
    if (tid < H) {
      float s = 0.f;
      for (int c = 0; c < H; ++c) s += W2[2 * H * H + tid * H + c] * W_ro[c];
      u[tid] = s;
    }
    __syncthreads();
    if (tid == 0) {
      float c2r = 0.f;
      for (int k = 0; k < H; ++k) c2r += b2[2 * H + k] * W_ro[k];
      float S = 0.f;
      for (int j = 0; j < N; ++j) S += sred[j];
      cp[0] = c2r * S + b_ro[0];
    }
  }
}

__global__ __launch_bounds__(256, 4)
void gnn_mfma(const float* __restrict__ x,
              const float* __restrict__ W_lift,
              const float* __restrict__ b_lift,
              const float* __restrict__ b1,
              const float* __restrict__ b2,
              const char* __restrict__ ws,
              float* __restrict__ out) {
  __shared__ f16 smem[4][N * RS];   // 40960 B exactly -> 4 blocks/CU

  const f16* adjf = (const f16*)(ws + WS_ADJF);
  const f16* w1t  = (const f16*)(ws + WS_W1T);
  const f16* w2t  = (const f16*)(ws + WS_W2T);
  const float* v  = (const float*)(ws + WS_V);
  const float* u  = (const float*)(ws + WS_U);
  const float* cp = (const float*)(ws + WS_C);

  const int tid  = threadIdx.x;
  const int wave = tid >> 6;
  const int lane = tid & 63;
  const int lrow = lane & 15;   // m/n index within a 16-tile
  const int quad = lane >> 4;   // 0..3
  const int b    = blockIdx.x * 4 + wave;

  f16* buf = &smem[wave][0];    // private slab: bufH rows n*RS; bufL rows f*LS (overlaid)

  const f32x4 zero = {0.f, 0.f, 0.f, 0.f};

  // ---- lift: 2 nodes per lane, H0 -> bufH (fp32 VALU; W_lift uniform -> s_loads)
  {
    const float* xr = x + (size_t)b * (N * 3) + lane * 6;
    const float2 xa = *(const float2*)(xr);
    const float2 xb = *(const float2*)(xr + 2);
    const float2 xc = *(const float2*)(xr + 4);
    const float c[2][3] = {{xa.x, xa.y, xb.x}, {xb.y, xc.x, xc.y}};
#pragma unroll
    for (int nn = 0; nn < 2; ++nn) {
      f16* row = buf + (lane * 2 + nn) * RS;
#pragma unroll
      for (int kk = 0; kk < 4; ++kk) {
        half8 hv;
#pragma unroll
        for (int k = 0; k < 8; ++k) {
          const int kc = kk * 8 + k;
          hv[k] = (f16)fmaf(c[nn][0], W_lift[kc],
                     fmaf(c[nn][1], W_lift[H + kc],
                     fmaf(c[nn][2], W_lift[2 * H + kc], b_lift[kc])));
        }
        *(half8*)(row + kk * 8) = hv;
      }
    }
  }

  // ---- layers 0,1 ----
  for (int l = 0; l < 2; ++l) {
    // Stage A: T^T = W1^T·H^T, written back in place (T[node][fmid])
    {
      const f16* w1l = w1t + l * H * H;
      const half8 a0 = *(const half8*)(w1l + lrow * H + quad * 8);
      const half8 a1 = *(const half8*)(w1l + (16 + lrow) * H + quad * 8);
      const float4 bb0 = *(const float4*)(b1 + l * H + quad * 4);
      const float4 bb1 = *(const float4*)(b1 + l * H + 16 + quad * 4);
#pragma unroll
      for (int g = 0; g < 8; ++g) {
        f16* row = buf + (g * 16 + lrow) * RS;
        const half8 bf = *(const half8*)(row + quad * 8);
        const f32x4 c0 = __builtin_amdgcn_mfma_f32_16x16x32_f16(a0, bf, zero, 0, 0, 0);
        const f32x4 c1 = __builtin_amdgcn_mfma_f32_16x16x32_f16(a1, bf, zero, 0, 0, 0);
        half4 t0, t1;
        t0[0] = (f16)fmaxf(c0[0] + bb0.x, 0.f); t0[1] = (f16)fmaxf(c0[1] + bb0.y, 0.f);
        t0[2] = (f16)fmaxf(c0[2] + bb0.z, 0.f); t0[3] = (f16)fmaxf(c0[3] + bb0.w, 0.f);
        t1[0] = (f16)fmaxf(c1[0] + bb1.x, 0.f); t1[1] = (f16)fmaxf(c1[1] + bb1.y, 0.f);
        t1[2] = (f16)fmaxf(c1[2] + bb1.z, 0.f); t1[3] = (f16)fmaxf(c1[3] + bb1.w, 0.f);
        *(half4*)(row + quad * 4)      = t0;
        *(half4*)(row + 16 + quad * 4) = t1;
      }
    }

    // Stage B: L = T·W2 -> bufL (L^T[fout][node]); preload ALL af before
    // writes so the bufL overlay cannot clobber unread T.
    {
      const f16* w2l = w2t + l * H * H;
      const half8 wb0 = *(const half8*)(w2l + lrow * H + quad * 8);
      const half8 wb1 = *(const half8*)(w2l + (16 + lrow) * H + quad * 8);
      const float bias0 = b2[l * H + lrow];
      const float bias1 = b2[l * H + 16 + lrow];
      half8 af[8];
#pragma unroll
      for (int m = 0; m < 8; ++m)
        af[m] = *(const half8*)(buf + (m * 16 + lrow) * RS + quad * 8);
#pragma unroll
      for (int m = 0; m < 8; ++m) {
        const f32x4 d0 = __builtin_amdgcn_mfma_f32_16x16x32_f16(af[m], wb0, zero, 0, 0, 0);
        const f32x4 d1 = __builtin_amdgcn_mfma_f32_16x16x32_f16(af[m], wb1, zero, 0, 0, 0);
        half4 o0, o1;
        o0[0] = (f16)(d0[0] + bias0); o0[1] = (f16)(d0[1] + bias0);
        o0[2] = (f16)(d0[2] + bias0); o0[3] = (f16)(d0[3] + bias0);
        o1[0] = (f16)(d1[0] + bias1); o1[1] = (f16)(d1[1] + bias1);
        o1[2] = (f16)(d1[2] + bias1); o1[3] = (f16)(d1[3] + bias1);
        *(half4*)(buf + lrow * LS + m * 16 + quad * 4)        = o0;
        *(half4*)(buf + (16 + lrow) * LS + m * 16 + quad * 4) = o1;
      }
    }

    // Stage C: H'^T = L^T·adj^T; af2 fully preloaded, then only global (adj)
    // reads in the loop -> H' writes may overwrite bufL freely.
    {
      half8 af2[2][4];
#pragma unroll
      for (int mt = 0; mt < 2; ++mt)
#pragma unroll
        for (int kt = 0; kt < 4; ++kt)
          af2[mt][kt] = *(const half8*)(buf + (mt * 16 + lrow) * LS + kt * 32 + quad * 8);
#pragma unroll
      for (int g = 0; g < 8; ++g) {
        f32x4 h0 = zero, h1 = zero;
#pragma unroll
        for (int kt = 0; kt < 4; ++kt) {
          const half8 bf = *(const half8*)(adjf + (g * 16 + lrow) * N + kt * 32 + quad * 8);
          h0 = __builtin_amdgcn_mfma_f32_16x16x32_f16(af2[0][kt], bf, h0, 0, 0, 0);
          h1 = __builtin_amdgcn_mfma_f32_16x16x32_f16(af2[1][kt], bf, h1, 0, 0, 0);
        }
        f16* row = buf + (g * 16 + lrow) * RS;
        half4 w0, w1;
        w0[0] = (f16)h0[0]; w0[1] = (f16)h0[1]; w0[2] = (f16)h0[2]; w0[3] = (f16)h0[3];
        w1[0] = (f16)h1[0]; w1[1] = (f16)h1[1]; w1[2] = (f16)h1[2]; w1[3] = (f16)h1[3];
        *(half4*)(row + quad * 4)      = w0;
        *(half4*)(row + 16 + quad * 4) = w1;
      }
    }
  }

  // ---- layer 2 + folded readout ----
  {
    const f16* w1l = w1t + 2 * H * H;
    const half8 a0 = *(const half8*)(w1l + lrow * H + quad * 8);
    const half8 a1 = *(const half8*)(w1l + (16 + lrow) * H + quad * 8);
    const float4 u0  = *(const float4*)(u + quad * 4);
    const float4 u1  = *(const float4*)(u + 16 + quad * 4);
    const float4 bb0 = *(const float4*)(b1 + 2 * H + quad * 4);
    const float4 bb1 = *(const float4*)(b1 + 2 * H + 16 + quad * 4);
    float partial = 0.f;
#pragma unroll
    for (int g = 0; g < 8; ++g) {
      const half8 bf = *(const half8*)(buf + (g * 16 + lrow) * RS + quad * 8);
      const f32x4 c0 = __builtin_amdgcn_mfma_f32_16x16x32_f16(a0, bf, zero, 0, 0, 0);
      const f32x4 c1 = __builtin_amdgcn_mfma_f32_16x16x32_f16(a1, bf, zero, 0, 0, 0);
      const float vn = v[g * 16 + lrow];
      partial += (fmaxf(c0[0] + bb0.x, 0.f) * u0.x + fmaxf(c0[1] + bb0.y, 0.f) * u0.y +
                  fmaxf(c0[2] + bb0.z, 0.f) * u0.z + fmaxf(c0[3] + bb0.w, 0.f) * u0.w +
                  fmaxf(c1[0] + bb1.x, 0.f) * u1.x + fmaxf(c1[1] + bb1.y, 0.f) * u1.y +
                  fmaxf(c1[2] + bb1.z, 0.f) * u1.z + fmaxf(c1[3] + bb1.w, 0.f) * u1.w) * vn;
    }
#pragma unroll
    for (int off = 32; off > 0; off >>= 1) partial += __shfl_down(partial, off, 64);
    if (lane == 0) out[b] = partial + cp[0];
  }
}

extern "C" void kernel_launch(void* const* d_in, const int* in_sizes, int n_in,
                              void* d_out, int out_size, void* d_ws, size_t ws_size,
                              hipStream_t stream) {
  const float* x      = (const float*)d_in[0];
  const float* adj    = (const float*)d_in[1];
  const float* W_lift = (const float*)d_in[2];
  const float* b_lift = (const float*)d_in[3];
  const float* W1     = (const float*)d_in[4];
  const float* b1     = (const float*)d_in[5];
  const float* W2     = (const float*)d_in[6];
  const float* b2     = (const float*)d_in[7];
  const float* W_ro   = (const float*)d_in[8];
  const float* b_ro   = (const float*)d_in[9];
  char* ws = (char*)d_ws;
  float* o = (float*)d_out;

  const int B = in_sizes[0] / (N * 3);   // 16384
  hipLaunchKernelGGL(prep, dim3(8), dim3(256), 0, stream,
                     adj, W1, W2, b2, W_ro, b_ro, ws);
  hipLaunchKernelGGL(gnn_mfma, dim3(B / 4), dim3(256), 0, stream,
                     x, W_lift, b_lift, b1, b2, (const char*)ws, o);
}